// Round 4
// baseline (243.590 us; speedup 1.0000x reference)
//
#include <hip/hip_runtime.h>
#include <hip/hip_bf16.h>
#include <math.h>

#define MEM_DIM 1024
#define N_CHILD 16384

#define BM 128          // n-rows per GEMM block
#define BN 64           // j-cols per GEMM block
#define BK 64
#define KITERS (MEM_DIM / BK)
#define NGEMM ((N_CHILD / BM) * (MEM_DIM / BN))   // 2048
#define NPART (N_CHILD / BM)                      // 128 partial rows

typedef __bf16 bf16_t;
typedef __bf16 bf16x4 __attribute__((ext_vector_type(4)));
typedef __bf16 bf16x8 __attribute__((ext_vector_type(8)));
typedef float f32x4 __attribute__((ext_vector_type(4)));

// ---------------- Kernel 0: gates (blocks 0..1023) + direct-fp32 fused GEMM ----
// R2 lesson: BN=64 is the latency-tolerant tile (BN=128 dropped occupancy
// 33->20.6% and regressed 68->90us). This round removes the fp32->bf16 cvt
// PASS: the GEMM stages child_h/W_fh fp32 directly (coalesced loads, in-reg
// cvt, XOR-swizzled ds_write_b64), so the 34MB hbf intermediate and its
// 102MB of traffic disappear. Accumulation is race-free partial stores
// (acc_part[128][1024], each written once) -> no global atomics, no init
// ordering, so gates ride along as leading blocks.
__global__ __launch_bounds__(256) void fused_main(
        const float* __restrict__ child_h, const float* __restrict__ W_fh,
        const float* __restrict__ child_c, const float* __restrict__ b_fh,
        const float* __restrict__ hsum,
        const float* __restrict__ W_ih, const float* __restrict__ b_ih,
        const float* __restrict__ W_uh, const float* __restrict__ b_uh,
        const float* __restrict__ W_oh, const float* __restrict__ b_oh,
        float* __restrict__ acc_part, float* __restrict__ iu_ws,
        float* __restrict__ o_ws) {
    __shared__ __align__(1024) bf16_t sA[BM * BK];   // 16 KB
    __shared__ __align__(1024) bf16_t sB[BN * BK];   // 8 KB
    __shared__ float sred[BN];
    __shared__ float red[3][4];

    const int tid = threadIdx.x;

    if (blockIdx.x < MEM_DIM) {
        // ---- gates: one block per output column j; float4 single-pass dot ----
        const int j = blockIdx.x;
        const float* wi = W_ih + (size_t)j * MEM_DIM;
        const float* wu = W_uh + (size_t)j * MEM_DIM;
        const float* wo = W_oh + (size_t)j * MEM_DIM;
        float4 h4  = *(const float4*)(hsum + tid * 4);
        float4 wi4 = *(const float4*)(wi + tid * 4);
        float4 wu4 = *(const float4*)(wu + tid * 4);
        float4 wo4 = *(const float4*)(wo + tid * 4);
        float si = wi4.x * h4.x + wi4.y * h4.y + wi4.z * h4.z + wi4.w * h4.w;
        float su = wu4.x * h4.x + wu4.y * h4.y + wu4.z * h4.z + wu4.w * h4.w;
        float so = wo4.x * h4.x + wo4.y * h4.y + wo4.z * h4.z + wo4.w * h4.w;
        for (int off = 32; off > 0; off >>= 1) {
            si += __shfl_down(si, off, 64);
            su += __shfl_down(su, off, 64);
            so += __shfl_down(so, off, 64);
        }
        const int wave = tid >> 6, lane = tid & 63;
        if (lane == 0) { red[0][wave] = si; red[1][wave] = su; red[2][wave] = so; }
        __syncthreads();
        if (tid == 0) {
            float ti = red[0][0] + red[0][1] + red[0][2] + red[0][3] + b_ih[j];
            float tu = red[1][0] + red[1][1] + red[1][2] + red[1][3] + b_uh[j];
            float to = red[2][0] + red[2][1] + red[2][2] + red[2][3] + b_oh[j];
            float iv = 1.f / (1.f + expf(-ti));
            float uv = tanhf(tu);
            float ov = 1.f / (1.f + expf(-to));
            iu_ws[j] = iv * uv;
            o_ws[j]  = ov;
        }
        return;
    }

    // ---- fused f-gate GEMM + column reduction ----
    const int b    = blockIdx.x - MEM_DIM;   // 0..2047 (1024%8==0 keeps b&7 == blockIdx&7)
    const int lane = tid & 63;
    const int wave = tid >> 6;
    const int wr = wave >> 1;        // n-half (64 rows)
    const int wc = wave & 1;         // j-half (32 cols)
    const int q  = lane >> 4;
    const int cl = lane & 15;

    // XCD-aware tile mapping: xcd = b&7; j sweeps fastest within an XCD so 16
    // consecutive same-XCD blocks share one A-panel (L2-local).
    const int xcd = b & 7;
    const int l   = b >> 3;          // 0..255
    const int jt  = l & 15;
    const int ntl = l >> 4;          // 0..15
    const int j0  = jt * BN;
    const int n0  = (xcd * 16 + ntl) * BM;
    const int part = xcd * 16 + ntl; // 0..127

    // --- staging mapping: 4 rows x 16 lanes per load instruction (coalesced) ---
    const int sr = lane >> 4;        // 0..3 row-in-group
    const int sc = lane & 15;        // 0..15 col lane (4 floats each)
    const float* gA = child_h + (size_t)(n0 + wave * 32 + sr) * MEM_DIM + sc * 4;
    const float* gB = W_fh    + (size_t)(j0 + wave * 16 + sr) * MEM_DIM + sc * 4;

    // LDS write byte offsets (loop-invariant): row r, col chunk c=sc>>1,
    // sub-half sc&1; byte = r*128 + ((c ^ (r&7))<<4) + ((sc&1)<<3).
    int wa[8], wb[4];
#pragma unroll
    for (int i = 0; i < 8; i++) {
        const int r = wave * 32 + i * 4 + sr;
        wa[i] = r * 128 + ((((sc >> 1) ^ (r & 7)) << 4) | ((sc & 1) << 3));
    }
#pragma unroll
    for (int i = 0; i < 4; i++) {
        const int r = wave * 16 + i * 4 + sr;
        wb[i] = r * 128 + ((((sc >> 1) ^ (r & 7)) << 4) | ((sc & 1) << 3));
    }

    f32x4 acc[4][2];
#pragma unroll
    for (int a = 0; a < 4; a++)
#pragma unroll
        for (int c = 0; c < 2; c++) acc[a][c] = (f32x4)0.0f;

    // --- main K-loop: iterations 0..KITERS-2 ---
#pragma unroll 1
    for (int k = 0; k < KITERS - 1; ++k) {
        const int ko = k * BK;
        float4 a4[8];
        float4 b4[4];
#pragma unroll
        for (int i = 0; i < 8; i++)
            a4[i] = *(const float4*)(gA + (size_t)i * 4 * MEM_DIM + ko);
#pragma unroll
        for (int i = 0; i < 4; i++)
            b4[i] = *(const float4*)(gB + (size_t)i * 4 * MEM_DIM + ko);
#pragma unroll
        for (int i = 0; i < 8; i++) {
            bf16x4 v = { (bf16_t)a4[i].x, (bf16_t)a4[i].y,
                         (bf16_t)a4[i].z, (bf16_t)a4[i].w };
            *(bf16x4*)((char*)sA + wa[i]) = v;
        }
#pragma unroll
        for (int i = 0; i < 4; i++) {
            bf16x4 v = { (bf16_t)b4[i].x, (bf16_t)b4[i].y,
                         (bf16_t)b4[i].z, (bf16_t)b4[i].w };
            *(bf16x4*)((char*)sB + wb[i]) = v;
        }
        __syncthreads();   // tiles ready

#pragma unroll
        for (int h = 0; h < 2; h++) {
            bf16x8 af[4], bfr[2];
#pragma unroll
            for (int mt = 0; mt < 4; mt++) {
                const int ra = wr * 64 + mt * 16 + cl;
                af[mt] = *(const bf16x8*)(&sA[ra * BK + (((4 * h + q) ^ (cl & 7)) * 8)]);
            }
#pragma unroll
            for (int nt = 0; nt < 2; nt++) {
                const int rb = wc * 32 + nt * 16 + cl;
                bfr[nt] = *(const bf16x8*)(&sB[rb * BK + (((4 * h + q) ^ (cl & 7)) * 8)]);
            }
#pragma unroll
            for (int mt = 0; mt < 4; mt++)
#pragma unroll
                for (int nt = 0; nt < 2; nt++)
                    acc[mt][nt] = __builtin_amdgcn_mfma_f32_16x16x32_bf16(
                        af[mt], bfr[nt], acc[mt][nt], 0, 0, 0);
        }
        __syncthreads();   // tiles consumed
    }

    // --- peeled last iteration: staging loads + child_c/bias prefetch overlap ---
    {
        const int ko = (KITERS - 1) * BK;
        float4 a4[8];
        float4 b4[4];
#pragma unroll
        for (int i = 0; i < 8; i++)
            a4[i] = *(const float4*)(gA + (size_t)i * 4 * MEM_DIM + ko);
#pragma unroll
        for (int i = 0; i < 4; i++)
            b4[i] = *(const float4*)(gB + (size_t)i * 4 * MEM_DIM + ko);

        float ccr[2][4][4];
        float biasr[2];
        {
            const float* ccp = child_c + (size_t)(n0 + wr * 64 + q * 4) * MEM_DIM
                                       + j0 + wc * 32 + cl;
#pragma unroll
            for (int nt = 0; nt < 2; nt++) {
                biasr[nt] = b_fh[j0 + wc * 32 + nt * 16 + cl];
#pragma unroll
                for (int mt = 0; mt < 4; mt++)
#pragma unroll
                    for (int r = 0; r < 4; r++)
                        ccr[nt][mt][r] = ccp[(size_t)(mt * 16 + r) * MEM_DIM + nt * 16];
            }
        }

#pragma unroll
        for (int i = 0; i < 8; i++) {
            bf16x4 v = { (bf16_t)a4[i].x, (bf16_t)a4[i].y,
                         (bf16_t)a4[i].z, (bf16_t)a4[i].w };
            *(bf16x4*)((char*)sA + wa[i]) = v;
        }
#pragma unroll
        for (int i = 0; i < 4; i++) {
            bf16x4 v = { (bf16_t)b4[i].x, (bf16_t)b4[i].y,
                         (bf16_t)b4[i].z, (bf16_t)b4[i].w };
            *(bf16x4*)((char*)sB + wb[i]) = v;
        }
        __syncthreads();   // drains staging (lgkm) AND child_c loads (vm)

#pragma unroll
        for (int h = 0; h < 2; h++) {
            bf16x8 af[4], bfr[2];
#pragma unroll
            for (int mt = 0; mt < 4; mt++) {
                const int ra = wr * 64 + mt * 16 + cl;
                af[mt] = *(const bf16x8*)(&sA[ra * BK + (((4 * h + q) ^ (cl & 7)) * 8)]);
            }
#pragma unroll
            for (int nt = 0; nt < 2; nt++) {
                const int rb = wc * 32 + nt * 16 + cl;
                bfr[nt] = *(const bf16x8*)(&sB[rb * BK + (((4 * h + q) ^ (cl & 7)) * 8)]);
            }
#pragma unroll
            for (int mt = 0; mt < 4; mt++)
#pragma unroll
                for (int nt = 0; nt < 2; nt++)
                    acc[mt][nt] = __builtin_amdgcn_mfma_f32_16x16x32_bf16(
                        af[mt], bfr[nt], acc[mt][nt], 0, 0, 0);
        }

        // --- epilogue: f = sigmoid(S+b), colsum over 128 rows, partial store ---
        if (tid < BN) sred[tid] = 0.0f;
        __syncthreads();

        float colsum[2] = {0.f, 0.f};
#pragma unroll
        for (int nt = 0; nt < 2; nt++) {
#pragma unroll
            for (int mt = 0; mt < 4; mt++) {
#pragma unroll
                for (int r = 0; r < 4; r++) {
                    // C/D layout: col = lane&15, row = q*4 + r
                    float s = acc[mt][nt][r] + biasr[nt];
                    float fg = 1.0f / (1.0f + __expf(-s));
                    colsum[nt] += fg * ccr[nt][mt][r];
                }
            }
            colsum[nt] += __shfl_xor(colsum[nt], 16, 64);
            colsum[nt] += __shfl_xor(colsum[nt], 32, 64);
        }
        if (q == 0) {
#pragma unroll
            for (int nt = 0; nt < 2; nt++)
                atomicAdd(&sred[wc * 32 + nt * 16 + cl], colsum[nt]);
        }
        __syncthreads();
        if (tid < BN)
            acc_part[(size_t)part * MEM_DIM + j0 + tid] = sred[tid];
    }
}

// ---------------- Kernel 1: finalize c, h (sums 128 partials + i*u) ----------------
__global__ __launch_bounds__(256) void finalize_kernel(
        const float* __restrict__ acc_part, const float* __restrict__ iu_ws,
        const float* __restrict__ o_ws, float* __restrict__ out) {
    const int j = blockIdx.x * 256 + threadIdx.x;
    float s = iu_ws[j];
#pragma unroll 8
    for (int p = 0; p < NPART; ++p)
        s += acc_part[(size_t)p * MEM_DIM + j];
    out[j] = s;
    out[MEM_DIM + j] = o_ws[j] * tanhf(s);
}

extern "C" void kernel_launch(void* const* d_in, const int* in_sizes, int n_in,
                              void* d_out, int out_size, void* d_ws, size_t ws_size,
                              hipStream_t stream) {
    const float* child_c = (const float*)d_in[0];
    const float* child_h = (const float*)d_in[1];
    const float* hsum    = (const float*)d_in[2];
    const float* W_ih    = (const float*)d_in[3];
    const float* b_ih    = (const float*)d_in[4];
    const float* W_fh    = (const float*)d_in[5];
    const float* b_fh    = (const float*)d_in[6];
    const float* W_uh    = (const float*)d_in[7];
    const float* b_uh    = (const float*)d_in[8];
    const float* W_oh    = (const float*)d_in[9];
    const float* b_oh    = (const float*)d_in[10];
    float* out = (float*)d_out;

    float* acc_part = (float*)d_ws;                      // 128*1024 f = 512 KB
    float* iu_ws    = acc_part + (size_t)NPART * MEM_DIM;  // 1024 f
    float* o_ws     = iu_ws + MEM_DIM;                   // 1024 f

    fused_main<<<MEM_DIM + NGEMM, 256, 0, stream>>>(
        child_h, W_fh, child_c, b_fh,
        hsum, W_ih, b_ih, W_uh, b_uh, W_oh, b_oh,
        acc_part, iu_ws, o_ws);
    finalize_kernel<<<MEM_DIM / 256, 256, 0, stream>>>(acc_part, iu_ws, o_ws, out);
}

// Round 5
// 218.423 us; speedup vs baseline: 1.1152x; 1.1152x over previous
//
#include <hip/hip_runtime.h>
#include <hip/hip_bf16.h>
#include <math.h>

#define MEM_DIM 1024
#define N_CHILD 16384

typedef __bf16 bf16_t;
typedef __bf16 bf16x4 __attribute__((ext_vector_type(4)));
typedef __bf16 bf16x8 __attribute__((ext_vector_type(8)));
typedef float f32x4 __attribute__((ext_vector_type(4)));

__device__ __forceinline__ void async_load16(const bf16_t* g, bf16_t* l) {
    __builtin_amdgcn_global_load_lds(
        (const __attribute__((address_space(1))) unsigned int*)g,
        (__attribute__((address_space(3))) unsigned int*)l,
        16, 0, 0);
}

template<int N> __device__ __forceinline__ void wait_vm() {
    if constexpr (N == 0)      asm volatile("s_waitcnt vmcnt(0)" ::: "memory");
    else if constexpr (N == 4) asm volatile("s_waitcnt vmcnt(4)" ::: "memory");
    else if constexpr (N == 8) asm volatile("s_waitcnt vmcnt(8)" ::: "memory");
}

__device__ __forceinline__ void block_barrier() {
    __builtin_amdgcn_sched_barrier(0);
    asm volatile("" ::: "memory");
    __builtin_amdgcn_s_barrier();
    asm volatile("" ::: "memory");
    __builtin_amdgcn_sched_barrier(0);
}

// ---------------- Kernel 0: prep = gates matvecs (blocks 0..1023) + fp32->bf16 cvt ----
// Verbatim R1 (harness-verified).
__global__ __launch_bounds__(256) void prep_kernel(
        const float* __restrict__ child_h, const float* __restrict__ W_fh,
        bf16_t* __restrict__ dst, int n8,
        const float* __restrict__ hsum,
        const float* __restrict__ W_ih, const float* __restrict__ b_ih,
        const float* __restrict__ W_uh, const float* __restrict__ b_uh,
        const float* __restrict__ W_oh, const float* __restrict__ b_oh,
        float* __restrict__ acc_c, float* __restrict__ o_ws) {
    const int tid = threadIdx.x;
    if (blockIdx.x < MEM_DIM) {
        const int j = blockIdx.x;
        const float* wi = W_ih + (size_t)j * MEM_DIM;
        const float* wu = W_uh + (size_t)j * MEM_DIM;
        const float* wo = W_oh + (size_t)j * MEM_DIM;
        float4 h4  = *(const float4*)(hsum + tid * 4);
        float4 wi4 = *(const float4*)(wi + tid * 4);
        float4 wu4 = *(const float4*)(wu + tid * 4);
        float4 wo4 = *(const float4*)(wo + tid * 4);
        float si = wi4.x * h4.x + wi4.y * h4.y + wi4.z * h4.z + wi4.w * h4.w;
        float su = wu4.x * h4.x + wu4.y * h4.y + wu4.z * h4.z + wu4.w * h4.w;
        float so = wo4.x * h4.x + wo4.y * h4.y + wo4.z * h4.z + wo4.w * h4.w;
        for (int off = 32; off > 0; off >>= 1) {
            si += __shfl_down(si, off, 64);
            su += __shfl_down(su, off, 64);
            so += __shfl_down(so, off, 64);
        }
        __shared__ float red[3][4];
        const int wave = tid >> 6, lane = tid & 63;
        if (lane == 0) { red[0][wave] = si; red[1][wave] = su; red[2][wave] = so; }
        __syncthreads();
        if (tid == 0) {
            float ti = red[0][0] + red[0][1] + red[0][2] + red[0][3] + b_ih[j];
            float tu = red[1][0] + red[1][1] + red[1][2] + red[1][3] + b_uh[j];
            float to = red[2][0] + red[2][1] + red[2][2] + red[2][3] + b_oh[j];
            float iv = 1.f / (1.f + expf(-ti));
            float uv = tanhf(tu);
            float ov = 1.f / (1.f + expf(-to));
            acc_c[j] = iv * uv;
            o_ws[j]  = ov;
        }
    } else {
        const int nA8 = (N_CHILD * MEM_DIM) / 8;
        int t = (blockIdx.x - MEM_DIM) * 256 + tid;
        if (t < n8) {
            const float* s = (t < nA8) ? (child_h + (size_t)t * 8)
                                       : (W_fh + (size_t)(t - nA8) * 8);
            float4 a = *(const float4*)s;
            float4 b = *(const float4*)(s + 4);
            bf16x8 o = { (bf16_t)a.x, (bf16_t)a.y, (bf16_t)a.z, (bf16_t)a.w,
                         (bf16_t)b.x, (bf16_t)b.y, (bf16_t)b.z, (bf16_t)b.w };
            *(bf16x8*)(dst + (size_t)t * 8) = o;
        }
    }
}

// ---------------- Kernel 1: 8-phase 256x256 fused f-gate GEMM ----------------
// T3+T4 schedule: 32 k-slices (32 wide), 4-slot LDS rotation per tensor,
// per slice 2 phases; counted vmcnt(8) once per slice (never 0 in loop);
// prefetch depth = 3 slices (~6 phases ~ HBM latency). 512 thr = 8 waves
// (2 row-halves x 4 col-quarters), per-wave C = 128x64 (acc 8x4 f32x4).
// Swizzle: LDS slot row stride 64B, chunk c holds global chunk c^(row&3);
// achieved with linear LDS dest + inverse-swizzled global src (gload_lds-legal).

// stage one 16KB slot (256 rows x 32 k bf16): 2 gload_lds per thread
__device__ __forceinline__ void stage_slot(const bf16_t* __restrict__ gbase,
                                           int row0, int s, bf16_t* lds_slot,
                                           int tid) {
    const int wave = tid >> 6;
    const int rr   = tid >> 2;                       // 0..127 row-in-issue
    const int cf   = ((tid & 3) ^ (rr & 3)) * 8;     // inverse-swizzled chunk
#pragma unroll
    for (int i = 0; i < 2; ++i) {
        const bf16_t* src = gbase + (size_t)(row0 + i * 128 + rr) * MEM_DIM
                          + s * 32 + cf;
        bf16_t* dst = lds_slot + i * 4096 + wave * 512;   // wave-uniform base
        async_load16(src, dst);
    }
}

template<int VMN, bool STG>
__device__ __forceinline__ void do_slice(
        int s, bf16_t* ldsA, bf16_t* ldsB,
        const bf16_t* __restrict__ hbf, const bf16_t* __restrict__ wbf,
        int n0, int j0, int tid, int wr, int wc, int q, int cl,
        f32x4 (&acc)[8][4]) {
    const int m = s & 3;
    const int koff  = (q ^ (cl & 3)) * 8;            // swizzled k-chunk read
    const int abase = m * 8192 + (wr * 128 + cl) * 32 + koff;
    const int bbase = m * 8192 + (wc * 64  + cl) * 32 + koff;
    bf16x8 af[8], bfr[2];

    // ---------- phase A: nt 0,1 ----------
#pragma unroll
    for (int mt = 0; mt < 8; ++mt)
        af[mt] = *(const bf16x8*)(&ldsA[abase + mt * 512]);
#pragma unroll
    for (int nt = 0; nt < 2; ++nt)
        bfr[nt] = *(const bf16x8*)(&ldsB[bbase + nt * 512]);
    if (STG) stage_slot(hbf, n0, s + 3, ldsA + ((s + 3) & 3) * 8192, tid);
    block_barrier();
    asm volatile("s_waitcnt lgkmcnt(0)" ::: "memory");
    __builtin_amdgcn_sched_barrier(0);
    __builtin_amdgcn_s_setprio(1);
#pragma unroll
    for (int mt = 0; mt < 8; ++mt) {
        acc[mt][0] = __builtin_amdgcn_mfma_f32_16x16x32_bf16(af[mt], bfr[0], acc[mt][0], 0, 0, 0);
        acc[mt][1] = __builtin_amdgcn_mfma_f32_16x16x32_bf16(af[mt], bfr[1], acc[mt][1], 0, 0, 0);
    }
    __builtin_amdgcn_s_setprio(0);
    block_barrier();

    // ---------- phase B: nt 2,3 (af reused from regs) ----------
#pragma unroll
    for (int nt = 0; nt < 2; ++nt)
        bfr[nt] = *(const bf16x8*)(&ldsB[bbase + (2 + nt) * 512]);
    if (STG) stage_slot(wbf, j0, s + 3, ldsB + ((s + 3) & 3) * 8192, tid);
    if constexpr (VMN >= 0) wait_vm<VMN>();          // slice s+1 landed; s+2,s+3 in flight
    block_barrier();
    asm volatile("s_waitcnt lgkmcnt(0)" ::: "memory");
    __builtin_amdgcn_sched_barrier(0);
    __builtin_amdgcn_s_setprio(1);
#pragma unroll
    for (int mt = 0; mt < 8; ++mt) {
        acc[mt][2] = __builtin_amdgcn_mfma_f32_16x16x32_bf16(af[mt], bfr[0], acc[mt][2], 0, 0, 0);
        acc[mt][3] = __builtin_amdgcn_mfma_f32_16x16x32_bf16(af[mt], bfr[1], acc[mt][3], 0, 0, 0);
    }
    __builtin_amdgcn_s_setprio(0);
    block_barrier();
}

__global__ __launch_bounds__(512, 2) void gemm8_kernel(
        const bf16_t* __restrict__ hbf, const bf16_t* __restrict__ wbf,
        const float* __restrict__ child_c, const float* __restrict__ b_fh,
        float* __restrict__ acc_part) {
    __shared__ __align__(1024) bf16_t ldsA[4 * 8192];   // 64 KB (4 slots)
    __shared__ __align__(1024) bf16_t ldsB[4 * 8192];   // 64 KB
    __shared__ float sred[256];

    const int tid  = threadIdx.x;
    const int lane = tid & 63;
    const int wave = tid >> 6;
    const int wr = wave >> 2;        // 0..1  row-half (128 rows)
    const int wc = wave & 3;         // 0..3  col-quarter (64 cols)
    const int q  = lane >> 4;
    const int cl = lane & 15;

    // XCD-chunked tile map: 256 blocks, 32/XCD; j sweeps fastest (4 j-tiles
    // share each A-panel in the XCD's L2).
    const int b   = blockIdx.x;
    const int xcd = b & 7;
    const int l   = b >> 3;          // 0..31
    const int jt  = l & 3;
    const int ntl = l >> 2;          // 0..7
    const int j0  = jt * 256;
    const int n0  = (xcd * 8 + ntl) * 256;
    const int part = xcd * 8 + ntl;  // 0..63

    f32x4 acc[8][4];
#pragma unroll
    for (int a = 0; a < 8; ++a)
#pragma unroll
        for (int c = 0; c < 4; ++c) acc[a][c] = (f32x4)0.0f;

    // --- prologue: stage slices 0,1,2 (12 instr/wave); ensure slice0 landed ---
#pragma unroll
    for (int s = 0; s < 3; ++s) {
        stage_slot(hbf, n0, s, ldsA + (s & 3) * 8192, tid);
        stage_slot(wbf, j0, s, ldsB + (s & 3) * 8192, tid);
    }
    wait_vm<8>();
    block_barrier();

    // --- main loop: slices 0..28 stage slice s+3; tail 29..31 drain ---
#pragma unroll 1
    for (int s = 0; s < 29; ++s)
        do_slice<8, true>(s, ldsA, ldsB, hbf, wbf, n0, j0, tid, wr, wc, q, cl, acc);
    do_slice<4,  false>(29, ldsA, ldsB, hbf, wbf, n0, j0, tid, wr, wc, q, cl, acc);
    do_slice<0,  false>(30, ldsA, ldsB, hbf, wbf, n0, j0, tid, wr, wc, q, cl, acc);
    do_slice<-1, false>(31, ldsA, ldsB, hbf, wbf, n0, j0, tid, wr, wc, q, cl, acc);

    // --- epilogue: f = sigmoid(S+b), fg*child_c colsum, race-free partials ---
    float colsum[4] = {0.f, 0.f, 0.f, 0.f};
#pragma unroll
    for (int nt = 0; nt < 4; ++nt) {
        const int j = j0 + wc * 64 + nt * 16 + cl;
        const float bias = b_fh[j];
#pragma unroll
        for (int mt = 0; mt < 8; ++mt) {
            const int nrow = n0 + wr * 128 + mt * 16 + q * 4;
            const float* ccp = child_c + (size_t)nrow * MEM_DIM + j;
#pragma unroll
            for (int rr = 0; rr < 4; ++rr) {
                // C/D layout: col = lane&15 (j), row = q*4 + rr (n)
                float sv = acc[mt][nt][rr] + bias;
                float fg = 1.0f / (1.0f + __expf(-sv));
                colsum[nt] += fg * ccp[(size_t)rr * MEM_DIM];
            }
        }
        colsum[nt] += __shfl_xor(colsum[nt], 16, 64);
        colsum[nt] += __shfl_xor(colsum[nt], 32, 64);
    }
    if (tid < 256) sred[tid] = 0.0f;
    __syncthreads();
    if (q == 0) {
#pragma unroll
        for (int nt = 0; nt < 4; ++nt)
            atomicAdd(&sred[wc * 64 + nt * 16 + cl], colsum[nt]);
    }
    __syncthreads();
    if (tid < 256)
        acc_part[(size_t)part * MEM_DIM + j0 + tid] = sred[tid];
}

// ---------------- Kernel 2: finalize c, h (sums 64 partials + i*u) ----------------
__global__ __launch_bounds__(256) void finalize2(
        const float* __restrict__ acc_part, const float* __restrict__ iu_ws,
        const float* __restrict__ o_ws, float* __restrict__ out) {
    const int j = blockIdx.x * 256 + threadIdx.x;
    float s = iu_ws[j];
#pragma unroll 8
    for (int p = 0; p < 64; ++p)
        s += acc_part[(size_t)p * MEM_DIM + j];
    out[j] = s;
    out[MEM_DIM + j] = o_ws[j] * tanhf(s);
}

// ---------------- Fallback path (ws too small) — R1 verbatim ----------------
__global__ void gates_kernel(const float* __restrict__ hsum,
                             const float* __restrict__ W_ih, const float* __restrict__ b_ih,
                             const float* __restrict__ W_uh, const float* __restrict__ b_uh,
                             const float* __restrict__ W_oh, const float* __restrict__ b_oh,
                             float* __restrict__ acc_c, float* __restrict__ o_ws) {
    const int j = blockIdx.x;
    const int tid = threadIdx.x;
    const float* wi = W_ih + (size_t)j * MEM_DIM;
    const float* wu = W_uh + (size_t)j * MEM_DIM;
    const float* wo = W_oh + (size_t)j * MEM_DIM;
    float si = 0.f, su = 0.f, so = 0.f;
    for (int k = tid; k < MEM_DIM; k += 256) {
        float hv = hsum[k];
        si += wi[k] * hv;
        su += wu[k] * hv;
        so += wo[k] * hv;
    }
    for (int off = 32; off > 0; off >>= 1) {
        si += __shfl_down(si, off, 64);
        su += __shfl_down(su, off, 64);
        so += __shfl_down(so, off, 64);
    }
    __shared__ float red[3][4];
    const int wave = tid >> 6, lane = tid & 63;
    if (lane == 0) { red[0][wave] = si; red[1][wave] = su; red[2][wave] = so; }
    __syncthreads();
    if (tid == 0) {
        float ti = red[0][0] + red[0][1] + red[0][2] + red[0][3] + b_ih[j];
        float tu = red[1][0] + red[1][1] + red[1][2] + red[1][3] + b_uh[j];
        float to = red[2][0] + red[2][1] + red[2][2] + red[2][3] + b_oh[j];
        acc_c[j] = (1.f / (1.f + expf(-ti))) * tanhf(tu);
        o_ws[j]  = 1.f / (1.f + expf(-to));
    }
}

#define LDS_STRIDE 40
__global__ __launch_bounds__(256) void fused_gemm_f32(
        const float* __restrict__ child_h, const float* __restrict__ child_c,
        const float* __restrict__ W_fh, const float* __restrict__ b_fh,
        float* __restrict__ acc_c) {
    __shared__ __align__(16) bf16_t sA[128 * LDS_STRIDE];
    __shared__ __align__(16) bf16_t sB[128 * LDS_STRIDE];
    __shared__ float sred[128];
    const int tid = threadIdx.x, lane = tid & 63, wave = tid >> 6;
    const int wr = wave >> 1, wc = wave & 1;
    const int j0 = blockIdx.x * 128, n0 = blockIdx.y * 128;
    const int q = lane >> 4, cl = lane & 15;
    f32x4 acc[4][4];
#pragma unroll
    for (int a = 0; a < 4; a++)
#pragma unroll
        for (int c = 0; c < 4; c++) acc[a][c] = (f32x4)0.0f;
    for (int k0 = 0; k0 < MEM_DIM; k0 += 32) {
#pragma unroll
        for (int i = 0; i < 4; i++) {
            int f = tid + i * 256, row = f >> 3, col = (f & 7) * 4;
            float4 va = *(const float4*)(child_h + (size_t)(n0 + row) * MEM_DIM + k0 + col);
            float4 vb = *(const float4*)(W_fh    + (size_t)(j0 + row) * MEM_DIM + k0 + col);
            bf16x4 ba = { (bf16_t)va.x, (bf16_t)va.y, (bf16_t)va.z, (bf16_t)va.w };
            bf16x4 bb = { (bf16_t)vb.x, (bf16_t)vb.y, (bf16_t)vb.z, (bf16_t)vb.w };
            *(bf16x4*)(&sA[row * LDS_STRIDE + col]) = ba;
            *(bf16x4*)(&sB[row * LDS_STRIDE + col]) = bb;
        }
        __syncthreads();
        bf16x8 af[4], bfr[4];
#pragma unroll
        for (int mt = 0; mt < 4; mt++) {
            af[mt]  = *(const bf16x8*)(&sA[(wr * 64 + mt * 16 + cl) * LDS_STRIDE + q * 8]);
            bfr[mt] = *(const bf16x8*)(&sB[(wc * 64 + mt * 16 + cl) * LDS_STRIDE + q * 8]);
        }
#pragma unroll
        for (int mt = 0; mt < 4; mt++)
#pragma unroll
            for (int nt = 0; nt < 4; nt++)
                acc[mt][nt] = __builtin_amdgcn_mfma_f32_16x16x32_bf16(af[mt], bfr[nt], acc[mt][nt], 0, 0, 0);
        __syncthreads();
    }
    if (tid < 128) sred[tid] = 0.0f;
    __syncthreads();
    float colsum[4] = {0.f, 0.f, 0.f, 0.f};
#pragma unroll
    for (int nt = 0; nt < 4; nt++) {
        const int col = j0 + wc * 64 + nt * 16 + cl;
        const float bias = b_fh[col];
#pragma unroll
        for (int mt = 0; mt < 4; mt++)
#pragma unroll
            for (int r = 0; r < 4; r++) {
                const int row = n0 + wr * 64 + mt * 16 + q * 4 + r;
                float s = acc[mt][nt][r] + bias;
                float fg = 1.0f / (1.0f + __expf(-s));
                colsum[nt] += fg * child_c[(size_t)row * MEM_DIM + col];
            }
        colsum[nt] += __shfl_xor(colsum[nt], 16, 64);
        colsum[nt] += __shfl_xor(colsum[nt], 32, 64);
    }
    if (q == 0)
#pragma unroll
        for (int nt = 0; nt < 4; nt++)
            atomicAdd(&sred[wc * 64 + nt * 16 + cl], colsum[nt]);
    __syncthreads();
    if (tid < 128) atomicAdd(&acc_c[j0 + tid], sred[tid]);
}

__global__ void finalize_old(const float* __restrict__ acc_c,
                             const float* __restrict__ o_ws,
                             float* __restrict__ out) {
    int t = blockIdx.x * 256 + threadIdx.x;
    if (t < MEM_DIM) {
        float cv = acc_c[t];
        float hv = o_ws[t] * tanhf(cv);
        out[t] = cv;
        out[MEM_DIM + t] = hv;
    }
}

extern "C" void kernel_launch(void* const* d_in, const int* in_sizes, int n_in,
                              void* d_out, int out_size, void* d_ws, size_t ws_size,
                              hipStream_t stream) {
    const float* child_c = (const float*)d_in[0];
    const float* child_h = (const float*)d_in[1];
    const float* hsum    = (const float*)d_in[2];
    const float* W_ih    = (const float*)d_in[3];
    const float* b_ih    = (const float*)d_in[4];
    const float* W_fh    = (const float*)d_in[5];
    const float* b_fh    = (const float*)d_in[6];
    const float* W_uh    = (const float*)d_in[7];
    const float* b_uh    = (const float*)d_in[8];
    const float* W_oh    = (const float*)d_in[9];
    const float* b_oh    = (const float*)d_in[10];
    float* out   = (float*)d_out;

    float* acc_c = (float*)d_ws;                         // 1024 f (i*u)
    float* o_ws  = acc_c + MEM_DIM;                      // 1024 f
    const size_t HBF_OFF   = 8192;                       // bytes
    const size_t HBF_BYTES = (size_t)N_CHILD * MEM_DIM * 2;   // 33.5 MB
    const size_t WBF_BYTES = (size_t)MEM_DIM * MEM_DIM * 2;   // 2 MB
    const size_t PART_BYTES = (size_t)64 * MEM_DIM * 4;       // 256 KB
    const size_t NEED = HBF_OFF + HBF_BYTES + WBF_BYTES + PART_BYTES;

    if (ws_size >= NEED) {
        bf16_t* hbf = (bf16_t*)((char*)d_ws + HBF_OFF);
        bf16_t* wbf = hbf + (size_t)N_CHILD * MEM_DIM;
        float* acc_part = (float*)(wbf + (size_t)MEM_DIM * MEM_DIM);
        const int n8 = (N_CHILD * MEM_DIM + MEM_DIM * MEM_DIM) / 8;  // 2,228,224
        const int cvtBlocks = (n8 + 255) / 256;                      // 8704
        prep_kernel<<<MEM_DIM + cvtBlocks, 256, 0, stream>>>(
            child_h, W_fh, hbf, n8,
            hsum, W_ih, b_ih, W_uh, b_uh, W_oh, b_oh, acc_c, o_ws);
        gemm8_kernel<<<256, 512, 0, stream>>>(hbf, wbf, child_c, b_fh, acc_part);
        finalize2<<<MEM_DIM / 256, 256, 0, stream>>>(acc_part, acc_c, o_ws, out);
    } else {
        gates_kernel<<<MEM_DIM, 256, 0, stream>>>(hsum, W_ih, b_ih, W_uh, b_uh,
                                                  W_oh, b_oh, acc_c, o_ws);
        dim3 grid(MEM_DIM / 128, N_CHILD / 128);
        fused_gemm_f32<<<grid, 256, 0, stream>>>(child_h, child_c, W_fh, b_fh, acc_c);
        finalize_old<<<(MEM_DIM + 255) / 256, 256, 0, stream>>>(acc_c, o_ws, out);
    }
}